// Round 9
// baseline (396.052 us; speedup 1.0000x reference)
//
#include <hip/hip_runtime.h>

#define NN 50000
#define NE 800000
#define NH 128
#define NO 64
#define NL 4
#define BN_EPS 1e-5f
#define NB1 ((NN + 255) / 256)   // 196 scan blocks
#define NGB (NN / 8)             // 6250 gather blocks (8 nodes/block)

typedef __attribute__((ext_vector_type(8))) short short8;
typedef __attribute__((ext_vector_type(4))) float f32x4;
typedef __attribute__((ext_vector_type(4))) unsigned int u32x4;

__device__ inline unsigned short f2bf(float f) {
    unsigned int u = __float_as_uint(f);
    return (unsigned short)((u + 0x7fffu + ((u >> 16) & 1u)) >> 16);
}
__device__ inline float bflo(unsigned int u) { return __uint_as_float(u << 16); }
__device__ inline float bfhi(unsigned int u) { return __uint_as_float(u & 0xffff0000u); }
__device__ inline unsigned pk(float a, float b) {
    return (unsigned)f2bf(a) | ((unsigned)f2bf(b) << 16);
}

// ---------- degree count into 4 replicated arrays + per-edge rank ----------
__global__ void k_degrank(const int* __restrict__ dst, int* __restrict__ deg_r,
                          int* __restrict__ rank) {
    int base = (blockIdx.x * 256 + threadIdx.x) * 2;
    if (base >= NE) return;
    int2 d2 = *(const int2*)&dst[base];
    int r0 = (base >> 9) & 3;
    int2 rr;
    rr.x = atomicAdd(&deg_r[r0 * NN + d2.x], 1);
    rr.y = atomicAdd(&deg_r[r0 * NN + d2.y], 1);
    *(int2*)&rank[base] = rr;
}

// ---------- scan phase 1: totals, dinv, per-r offsets ----------
__global__ void k_scan1(const int* __restrict__ deg_r, int* __restrict__ off,
                        int* __restrict__ aux, float* __restrict__ dinv,
                        int* __restrict__ degT, int* __restrict__ offR) {
    __shared__ int ls[256];
    int i = blockIdx.x * 256 + threadIdx.x;
    int c0 = 0, c1 = 0, c2 = 0, c3 = 0;
    if (i < NN) {
        c0 = deg_r[i]; c1 = deg_r[NN + i];
        c2 = deg_r[2 * NN + i]; c3 = deg_r[3 * NN + i];
    }
    int v = c0 + c1 + c2 + c3;
    ls[threadIdx.x] = v;
    __syncthreads();
    for (int s = 1; s < 256; s <<= 1) {
        int t = (threadIdx.x >= s) ? ls[threadIdx.x - s] : 0;
        __syncthreads();
        ls[threadIdx.x] += t;
        __syncthreads();
    }
    if (i < NN) {
        off[i] = ls[threadIdx.x] - v;       // block-local exclusive
        dinv[i] = rsqrtf((float)v + 1.0f);  // +1 self loop
        degT[i] = v;
        offR[i] = 0;
        offR[NN + i] = c0;
        offR[2 * NN + i] = c0 + c1;
        offR[3 * NN + i] = c0 + c1 + c2;
    }
    if (threadIdx.x == 255) aux[blockIdx.x] = ls[255];
}

__global__ void k_scan2(int* __restrict__ aux) {
    __shared__ int ls[256];
    int v = (threadIdx.x < NB1) ? aux[threadIdx.x] : 0;
    ls[threadIdx.x] = v;
    __syncthreads();
    for (int s = 1; s < 256; s <<= 1) {
        int t = (threadIdx.x >= s) ? ls[threadIdx.x - s] : 0;
        __syncthreads();
        ls[threadIdx.x] += t;
        __syncthreads();
    }
    if (threadIdx.x < NB1) aux[threadIdx.x] = ls[threadIdx.x] - v;
}

// ---------- CSR fill (no atomics), 4 edges/thread (quad shares one r-group) ----------
__global__ void k_fill(const int* __restrict__ src, const int* __restrict__ dst,
                       const int* __restrict__ off, const int* __restrict__ aux,
                       const int* __restrict__ offR, const int* __restrict__ rank,
                       int* __restrict__ csr) {
    int base = (blockIdx.x * 256 + threadIdx.x) * 4;
    if (base >= NE) return;
    int4 d4 = *(const int4*)&dst[base];
    int4 r4 = *(const int4*)&rank[base];
    int4 s4 = *(const int4*)&src[base];
    const int* oR = offR + ((base >> 9) & 3) * NN;   // 512 % 4 == 0 -> quad shares group
    csr[off[d4.x] + aux[d4.x >> 8] + oR[d4.x] + r4.x] = s4.x;
    csr[off[d4.y] + aux[d4.y >> 8] + oR[d4.y] + r4.y] = s4.y;
    csr[off[d4.z] + aux[d4.z >> 8] + oR[d4.z] + r4.z] = s4.z;
    csr[off[d4.w] + aux[d4.w >> 8] + oR[d4.w] + r4.w] = s4.w;
}

// ---------- pack W + Wout -> MFMA B-fragment order, bf16 ----------
__global__ void k_pack(const float* __restrict__ Ws, const float* __restrict__ Wout,
                       unsigned short* __restrict__ Wpk, unsigned short* __restrict__ Wopk) {
    int t = blockIdx.x * 256 + threadIdx.x;
    if (t < NL * 16384) {
        int l = t >> 14, r = t & 16383;
        int ks = r >> 12, ct = (r >> 9) & 7, lane = (r >> 3) & 63, i = r & 7;
        int k = ks * 32 + (lane >> 4) * 8 + i;
        int n = ct * 16 + (lane & 15);
        Wpk[t] = f2bf(Ws[l * 16384 + k * 128 + n]);
    } else if (t < NL * 16384 + 8192) {
        int r = t - NL * 16384;
        int ks = r >> 11, ct = (r >> 9) & 3, lane = (r >> 3) & 63, i = r & 7;
        int k = ks * 32 + (lane >> 4) * 8 + i;
        int n = ct * 16 + (lane & 15);
        Wopk[r] = f2bf(Wout[k * 64 + n]);
    }
}

// ---------- layer-0 GEMM: Hd(bf16) = (x_f32 @ W0) * dinv ----------
__global__ __launch_bounds__(256) void k_fg0(const float* __restrict__ X,
                                             const unsigned short* __restrict__ Wpk,
                                             const float* __restrict__ dinv,
                                             unsigned short* __restrict__ Hd) {
    int w = threadIdx.x >> 6, l = threadIdx.x & 63;
    int row0 = blockIdx.x * 64 + w * 16;
    int lo = l & 15, hi = l >> 4;
    int arow = row0 + lo;
    int crow = (arow < NN) ? arow : NN - 1;
    short8 frag[4];
#pragma unroll
    for (int g = 0; g < 4; g++) {
        int cs = g * 32 + hi * 8;
        float4 p0 = *(const float4*)&X[(size_t)crow * NH + cs];
        float4 p1 = *(const float4*)&X[(size_t)crow * NH + cs + 4];
        short8 f;
        f[0] = (short)f2bf(p0.x); f[1] = (short)f2bf(p0.y);
        f[2] = (short)f2bf(p0.z); f[3] = (short)f2bf(p0.w);
        f[4] = (short)f2bf(p1.x); f[5] = (short)f2bf(p1.y);
        f[6] = (short)f2bf(p1.z); f[7] = (short)f2bf(p1.w);
        frag[g] = f;
    }
    const short8* Wv = (const short8*)Wpk;
    int srow = row0 + hi * 4;
    float dv[4];
#pragma unroll
    for (int r = 0; r < 4; r++) dv[r] = (srow + r < NN) ? dinv[srow + r] : 0.0f;
#pragma unroll
    for (int ct = 0; ct < 8; ct++) {
        f32x4 acc = {0.0f, 0.0f, 0.0f, 0.0f};
#pragma unroll
        for (int g = 0; g < 4; g++)
            acc = __builtin_amdgcn_mfma_f32_16x16x32_bf16(frag[g], Wv[(g * 8 + ct) * 64 + l], acc, 0, 0, 0);
        int col = ct * 16 + lo;
#pragma unroll
        for (int r = 0; r < 4; r++) {
            int grow = srow + r;
            if (grow < NN) Hd[grow * NH + col] = f2bf(acc[r] * dv[r]);
        }
    }
}

// ---------- fused: x_l = BN+ReLU+res(AGG,prev); Hd = (x_l @ W) * dinv ----------
__global__ __launch_bounds__(256) void k_fg(const unsigned short* __restrict__ AGGb,
                                            const float* __restrict__ scale,
                                            const float* __restrict__ shift,
                                            const float* __restrict__ Xprev,
                                            float* __restrict__ Xout,
                                            const unsigned short* __restrict__ Wpk,
                                            const float* __restrict__ dinv,
                                            unsigned short* __restrict__ Hd) {
    int w = threadIdx.x >> 6, l = threadIdx.x & 63;
    int row0 = blockIdx.x * 64 + w * 16;
    int lo = l & 15, hi = l >> 4;
    int arow = row0 + lo;
    bool valid = arow < NN;
    int crow = valid ? arow : NN - 1;
    short8 frag[4];
#pragma unroll
    for (int g = 0; g < 4; g++) {
        int cs = g * 32 + hi * 8;
        uint4 ab = *(const uint4*)&AGGb[(size_t)crow * NH + cs];
        float4 p0 = *(const float4*)&Xprev[(size_t)crow * NH + cs];
        float4 p1 = *(const float4*)&Xprev[(size_t)crow * NH + cs + 4];
        float4 sc0 = *(const float4*)&scale[cs];
        float4 sc1 = *(const float4*)&scale[cs + 4];
        float4 sh0 = *(const float4*)&shift[cs];
        float4 sh1 = *(const float4*)&shift[cs + 4];
        float o0 = fmaxf(fmaf(bflo(ab.x), sc0.x, sh0.x), 0.0f) + p0.x;
        float o1 = fmaxf(fmaf(bfhi(ab.x), sc0.y, sh0.y), 0.0f) + p0.y;
        float o2 = fmaxf(fmaf(bflo(ab.y), sc0.z, sh0.z), 0.0f) + p0.z;
        float o3 = fmaxf(fmaf(bfhi(ab.y), sc0.w, sh0.w), 0.0f) + p0.w;
        float o4 = fmaxf(fmaf(bflo(ab.z), sc1.x, sh1.x), 0.0f) + p1.x;
        float o5 = fmaxf(fmaf(bfhi(ab.z), sc1.y, sh1.y), 0.0f) + p1.y;
        float o6 = fmaxf(fmaf(bflo(ab.w), sc1.z, sh1.z), 0.0f) + p1.z;
        float o7 = fmaxf(fmaf(bfhi(ab.w), sc1.w, sh1.w), 0.0f) + p1.w;
        if (valid) {
            float4 s0 = {o0, o1, o2, o3}, s1 = {o4, o5, o6, o7};
            *(float4*)&Xout[(size_t)arow * NH + cs] = s0;
            *(float4*)&Xout[(size_t)arow * NH + cs + 4] = s1;
        }
        short8 f;
        f[0] = (short)f2bf(o0); f[1] = (short)f2bf(o1);
        f[2] = (short)f2bf(o2); f[3] = (short)f2bf(o3);
        f[4] = (short)f2bf(o4); f[5] = (short)f2bf(o5);
        f[6] = (short)f2bf(o6); f[7] = (short)f2bf(o7);
        frag[g] = f;
    }
    const short8* Wv = (const short8*)Wpk;
    int srow = row0 + hi * 4;
    float dv[4];
#pragma unroll
    for (int r = 0; r < 4; r++) dv[r] = (srow + r < NN) ? dinv[srow + r] : 0.0f;
#pragma unroll
    for (int ct = 0; ct < 8; ct++) {
        f32x4 acc = {0.0f, 0.0f, 0.0f, 0.0f};
#pragma unroll
        for (int g = 0; g < 4; g++)
            acc = __builtin_amdgcn_mfma_f32_16x16x32_bf16(frag[g], Wv[(g * 8 + ct) * 64 + l], acc, 0, 0, 0);
        int col = ct * 16 + lo;
#pragma unroll
        for (int r = 0; r < 4; r++) {
            int grow = srow + r;
            if (grow < NN) Hd[grow * NH + col] = f2bf(acc[r] * dv[r]);
        }
    }
}

// ---------- fused final: x_4 = BN+ReLU+res; out = x_4 @ Wout + bout ----------
__global__ __launch_bounds__(256) void k_fgout(const unsigned short* __restrict__ AGGb,
                                               const float* __restrict__ scale,
                                               const float* __restrict__ shift,
                                               const float* __restrict__ Xprev,
                                               const unsigned short* __restrict__ Wpk,
                                               const float* __restrict__ b,
                                               float* __restrict__ out) {
    int w = threadIdx.x >> 6, l = threadIdx.x & 63;
    int row0 = blockIdx.x * 64 + w * 16;
    int lo = l & 15, hi = l >> 4;
    int arow = row0 + lo;
    int crow = (arow < NN) ? arow : NN - 1;
    short8 frag[4];
#pragma unroll
    for (int g = 0; g < 4; g++) {
        int cs = g * 32 + hi * 8;
        uint4 ab = *(const uint4*)&AGGb[(size_t)crow * NH + cs];
        float4 p0 = *(const float4*)&Xprev[(size_t)crow * NH + cs];
        float4 p1 = *(const float4*)&Xprev[(size_t)crow * NH + cs + 4];
        float4 sc0 = *(const float4*)&scale[cs];
        float4 sc1 = *(const float4*)&scale[cs + 4];
        float4 sh0 = *(const float4*)&shift[cs];
        float4 sh1 = *(const float4*)&shift[cs + 4];
        short8 f;
        f[0] = (short)f2bf(fmaxf(fmaf(bflo(ab.x), sc0.x, sh0.x), 0.0f) + p0.x);
        f[1] = (short)f2bf(fmaxf(fmaf(bfhi(ab.x), sc0.y, sh0.y), 0.0f) + p0.y);
        f[2] = (short)f2bf(fmaxf(fmaf(bflo(ab.y), sc0.z, sh0.z), 0.0f) + p0.z);
        f[3] = (short)f2bf(fmaxf(fmaf(bfhi(ab.y), sc0.w, sh0.w), 0.0f) + p0.w);
        f[4] = (short)f2bf(fmaxf(fmaf(bflo(ab.z), sc1.x, sh1.x), 0.0f) + p1.x);
        f[5] = (short)f2bf(fmaxf(fmaf(bfhi(ab.z), sc1.y, sh1.y), 0.0f) + p1.y);
        f[6] = (short)f2bf(fmaxf(fmaf(bflo(ab.w), sc1.z, sh1.z), 0.0f) + p1.z);
        f[7] = (short)f2bf(fmaxf(fmaf(bfhi(ab.w), sc1.w, sh1.w), 0.0f) + p1.w);
        frag[g] = f;
    }
    const short8* Wv = (const short8*)Wpk;
    int srow = row0 + hi * 4;
#pragma unroll
    for (int ct = 0; ct < 4; ct++) {
        f32x4 acc = {0.0f, 0.0f, 0.0f, 0.0f};
#pragma unroll
        for (int g = 0; g < 4; g++)
            acc = __builtin_amdgcn_mfma_f32_16x16x32_bf16(frag[g], Wv[(g * 4 + ct) * 64 + l], acc, 0, 0, 0);
        int col = ct * 16 + lo;
        float bb = b[col];
#pragma unroll
        for (int r = 0; r < 4; r++) {
            int grow = srow + r;
            if (grow < NN) out[grow * NO + col] = acc[r] + bb;
        }
    }
}

// ---------- CSR gather + fused BN partial stats ----------
// 8 nodes/block, 32 threads/node: 2 halves x 16 quarter-threads; each half
// runs a 4-deep unrolled loop over half the edge list -> 8 rows in flight/node.
__global__ __launch_bounds__(256) void k_gather(const unsigned short* __restrict__ Hd,
                                                const int* __restrict__ csr,
                                                const int* __restrict__ off,
                                                const int* __restrict__ aux,
                                                const int* __restrict__ degT,
                                                const float* __restrict__ dinv,
                                                unsigned short* __restrict__ AGGb,
                                                float* __restrict__ partial) {
    int b = blockIdx.x;
    int slot = threadIdx.x >> 5;           // 8 nodes per block
    int half = (threadIdx.x >> 4) & 1;
    int q = threadIdx.x & 15;
    int g = b * 8 + slot;                  // NN % 8 == 0, always valid
    const u32x4* Hv = (const u32x4*)Hd;
    int o = off[g] + aux[g >> 8];
    int d = degT[g];
    float a0 = 0, a1 = 0, a2 = 0, a3 = 0, a4 = 0, a5 = 0, a6 = 0, a7 = 0;
    if (!half) {   // self term counted once
        u32x4 h = Hv[g * 16 + q];
        a0 = bflo(h.x); a1 = bfhi(h.x);
        a2 = bflo(h.y); a3 = bfhi(h.y);
        a4 = bflo(h.z); a5 = bfhi(h.z);
        a6 = bflo(h.w); a7 = bfhi(h.w);
    }
    int dh = d >> 1;
    int j = half ? dh : 0;
    int je = half ? d : dh;
    for (; j + 4 <= je; j += 4) {
        int s0 = __builtin_nontemporal_load(&csr[o + j]);
        int s1 = __builtin_nontemporal_load(&csr[o + j + 1]);
        int s2 = __builtin_nontemporal_load(&csr[o + j + 2]);
        int s3 = __builtin_nontemporal_load(&csr[o + j + 3]);
        u32x4 h0 = Hv[s0 * 16 + q];
        u32x4 h1 = Hv[s1 * 16 + q];
        u32x4 h2 = Hv[s2 * 16 + q];
        u32x4 h3 = Hv[s3 * 16 + q];
        a0 += (bflo(h0.x) + bflo(h1.x)) + (bflo(h2.x) + bflo(h3.x));
        a1 += (bfhi(h0.x) + bfhi(h1.x)) + (bfhi(h2.x) + bfhi(h3.x));
        a2 += (bflo(h0.y) + bflo(h1.y)) + (bflo(h2.y) + bflo(h3.y));
        a3 += (bfhi(h0.y) + bfhi(h1.y)) + (bfhi(h2.y) + bfhi(h3.y));
        a4 += (bflo(h0.z) + bflo(h1.z)) + (bflo(h2.z) + bflo(h3.z));
        a5 += (bfhi(h0.z) + bfhi(h1.z)) + (bfhi(h2.z) + bfhi(h3.z));
        a6 += (bflo(h0.w) + bflo(h1.w)) + (bflo(h2.w) + bflo(h3.w));
        a7 += (bfhi(h0.w) + bfhi(h1.w)) + (bfhi(h2.w) + bfhi(h3.w));
    }
    for (; j < je; j++) {
        int s0 = __builtin_nontemporal_load(&csr[o + j]);
        u32x4 h0 = Hv[s0 * 16 + q];
        a0 += bflo(h0.x); a1 += bfhi(h0.x);
        a2 += bflo(h0.y); a3 += bfhi(h0.y);
        a4 += bflo(h0.z); a5 += bfhi(h0.z);
        a6 += bflo(h0.w); a7 += bfhi(h0.w);
    }
    // combine halves (lane ^ 16 flips half, same node, same q)
    a0 += __shfl_xor(a0, 16); a1 += __shfl_xor(a1, 16);
    a2 += __shfl_xor(a2, 16); a3 += __shfl_xor(a3, 16);
    a4 += __shfl_xor(a4, 16); a5 += __shfl_xor(a5, 16);
    a6 += __shfl_xor(a6, 16); a7 += __shfl_xor(a7, 16);
    float dv = dinv[g];
    a0 *= dv; a1 *= dv; a2 *= dv; a3 *= dv;
    a4 *= dv; a5 *= dv; a6 *= dv; a7 *= dv;
    if (!half) {
        u32x4 u;
        u.x = pk(a0, a1); u.y = pk(a2, a3);
        u.z = pk(a4, a5); u.w = pk(a6, a7);
        __builtin_nontemporal_store(u, &((u32x4*)AGGb)[g * 16 + q]);
    }
    // ---- fused BN partial stats ----
    float t0 = a0 * a0, t1 = a1 * a1, t2 = a2 * a2, t3 = a3 * a3;
    float t4 = a4 * a4, t5 = a5 * a5, t6 = a6 * a6, t7 = a7 * a7;
    // lane ^ 32 flips node-in-wave; values already duplicated across halves
#define RED(v) v += __shfl_xor(v, 32);
    RED(a0) RED(a1) RED(a2) RED(a3) RED(a4) RED(a5) RED(a6) RED(a7)
    RED(t0) RED(t1) RED(t2) RED(t3) RED(t4) RED(t5) RED(t6) RED(t7)
#undef RED
    __shared__ float ws[4][16][16];
    int wv = threadIdx.x >> 6, lane = threadIdx.x & 63;
    if (lane < 16) {
        ws[wv][lane][0] = a0; ws[wv][lane][1] = a1;
        ws[wv][lane][2] = a2; ws[wv][lane][3] = a3;
        ws[wv][lane][4] = a4; ws[wv][lane][5] = a5;
        ws[wv][lane][6] = a6; ws[wv][lane][7] = a7;
        ws[wv][lane][8] = t0; ws[wv][lane][9] = t1;
        ws[wv][lane][10] = t2; ws[wv][lane][11] = t3;
        ws[wv][lane][12] = t4; ws[wv][lane][13] = t5;
        ws[wv][lane][14] = t6; ws[wv][lane][15] = t7;
    }
    __syncthreads();
    if (threadIdx.x < 16) {
        int qq = threadIdx.x;
#pragma unroll
        for (int k = 0; k < 8; k++) {
            float sv = ws[0][qq][k] + ws[1][qq][k] + ws[2][qq][k] + ws[3][qq][k];
            float qv = ws[0][qq][k + 8] + ws[1][qq][k + 8] + ws[2][qq][k + 8] + ws[3][qq][k + 8];
            __builtin_nontemporal_store(sv, &partial[(size_t)b * 256 + qq * 8 + k]);
            __builtin_nontemporal_store(qv, &partial[(size_t)b * 256 + 128 + qq * 8 + k]);
        }
    }
}

// ---------- reduce partials -> scale/shift ----------
__global__ __launch_bounds__(256) void k_statred(const float* __restrict__ partial,
                                                 const float* __restrict__ gamma,
                                                 const float* __restrict__ beta,
                                                 float* __restrict__ scale,
                                                 float* __restrict__ shift) {
    int s = blockIdx.x;   // column 0..127
    int t = threadIdx.x;
    float sum = 0.0f, sq = 0.0f;
    for (int k = t; k < NGB; k += 256) {
        sum += partial[(size_t)k * 256 + s];
        sq  += partial[(size_t)k * 256 + 128 + s];
    }
    __shared__ float ls[256], lq[256];
    ls[t] = sum; lq[t] = sq;
    __syncthreads();
    for (int st = 128; st > 0; st >>= 1) {
        if (t < st) { ls[t] += ls[t + st]; lq[t] += lq[t + st]; }
        __syncthreads();
    }
    if (t == 0) {
        float mean = ls[0] * (1.0f / NN);
        float var = lq[0] * (1.0f / NN) - mean * mean;
        float istd = rsqrtf(var + BN_EPS);
        float sc = istd * gamma[s];
        scale[s] = sc;
        shift[s] = beta[s] - mean * sc;
    }
}

extern "C" void kernel_launch(void* const* d_in, const int* in_sizes, int n_in,
                              void* d_out, int out_size, void* d_ws, size_t ws_size,
                              hipStream_t stream) {
    const float* x    = (const float*)d_in[0];
    const int*   ei   = (const int*)d_in[1];
    const float* Ws   = (const float*)d_in[2];
    const float* gam  = (const float*)d_in[4];
    const float* bet  = (const float*)d_in[5];
    const float* Wout = (const float*)d_in[6];
    const float* bout = (const float*)d_in[7];
    float* out = (float*)d_out;

    const int* src = ei;
    const int* dst = ei + NE;

    char* p = (char*)d_ws;
    auto alloc = [&](size_t bytes) { char* r = p; p += (bytes + 255) & ~(size_t)255; return r; };
    int*   deg_r = (int*)alloc((size_t)4 * NN * 4);
    int*   offR  = (int*)alloc((size_t)4 * NN * 4);
    int*   degT  = (int*)alloc(NN * 4);
    int*   off   = (int*)alloc(NN * 4);
    int*   rank  = (int*)alloc((size_t)NE * 4);
    int*   aux   = (int*)alloc(256 * 4);
    int*   csr   = (int*)alloc((size_t)NE * 4);
    float* dinv  = (float*)alloc(NN * 4);
    float* XA    = (float*)alloc((size_t)NN * NH * 4);
    float* XB    = (float*)alloc((size_t)NN * NH * 4);
    unsigned short* Hd   = (unsigned short*)alloc((size_t)NN * NH * 2);
    unsigned short* AGGb = (unsigned short*)alloc((size_t)NN * NH * 2);
    unsigned short* Wpk  = (unsigned short*)alloc((size_t)NL * NH * NH * 2);
    unsigned short* Wopk = (unsigned short*)alloc((size_t)NH * NO * 2);
    float* partial = (float*)alloc((size_t)NGB * 256 * 4);   // 6.4MB
    float* scale = (float*)alloc(NH * 4);
    float* shift = (float*)alloc(NH * 4);

    // ---- preprocessing ----
    hipMemsetAsync(deg_r, 0, (size_t)4 * NN * 4, stream);
    k_degrank<<<(NE / 2 + 255) / 256, 256, 0, stream>>>(dst, deg_r, rank);
    k_scan1<<<NB1, 256, 0, stream>>>(deg_r, off, aux, dinv, degT, offR);
    k_scan2<<<1, 256, 0, stream>>>(aux);
    k_fill<<<(NE / 4 + 255) / 256, 256, 0, stream>>>(src, dst, off, aux, offR, rank, csr);
    k_pack<<<(NL * 16384 + 8192 + 255) / 256, 256, 0, stream>>>(Ws, Wout, Wpk, Wopk);

    const int GB = (NN + 63) / 64;

    // ---- layer 0 GEMM from f32 input ----
    k_fg0<<<GB, 256, 0, stream>>>(x, Wpk, dinv, Hd);

    const float* xprev = x;
    for (int l = 0; l < NL; l++) {
        k_gather<<<NGB, 256, 0, stream>>>(Hd, csr, off, aux, degT, dinv, AGGb, partial);
        k_statred<<<128, 256, 0, stream>>>(partial, gam + l * NH, bet + l * NH, scale, shift);
        if (l < NL - 1) {
            float* Xout = (l & 1) ? XB : XA;
            k_fg<<<GB, 256, 0, stream>>>(AGGb, scale, shift, xprev, Xout,
                                         Wpk + (size_t)(l + 1) * 16384, dinv, Hd);
            xprev = Xout;
        } else {
            k_fgout<<<GB, 256, 0, stream>>>(AGGb, scale, shift, xprev, Wopk, bout, out);
        }
    }
}

// Round 10
// 322.355 us; speedup vs baseline: 1.2286x; 1.2286x over previous
//
#include <hip/hip_runtime.h>

#define NN 50000
#define NE 800000
#define NH 128
#define NO 64
#define NL 4
#define BN_EPS 1e-5f
#define NB1 ((NN + 255) / 256)   // 196 scan blocks
#define NGB (NN / 16)            // 3125 gather blocks (16 nodes/block)

typedef __attribute__((ext_vector_type(8))) short short8;
typedef __attribute__((ext_vector_type(4))) float f32x4;

__device__ inline unsigned short f2bf(float f) {
    unsigned int u = __float_as_uint(f);
    return (unsigned short)((u + 0x7fffu + ((u >> 16) & 1u)) >> 16);
}
__device__ inline float bflo(unsigned int u) { return __uint_as_float(u << 16); }
__device__ inline float bfhi(unsigned int u) { return __uint_as_float(u & 0xffff0000u); }
__device__ inline unsigned pk(float a, float b) {
    return (unsigned)f2bf(a) | ((unsigned)f2bf(b) << 16);
}

// ---------- degree count into 4 replicated arrays + per-edge rank ----------
__global__ void k_degrank(const int* __restrict__ dst, int* __restrict__ deg_r,
                          int* __restrict__ rank) {
    int base = (blockIdx.x * 256 + threadIdx.x) * 2;
    if (base >= NE) return;
    int2 d2 = *(const int2*)&dst[base];
    int r0 = (base >> 9) & 3;
    int2 rr;
    rr.x = atomicAdd(&deg_r[r0 * NN + d2.x], 1);
    rr.y = atomicAdd(&deg_r[r0 * NN + d2.y], 1);
    *(int2*)&rank[base] = rr;
}

// ---------- scan phase 1: totals, dinv, per-r offsets ----------
__global__ void k_scan1(const int* __restrict__ deg_r, int* __restrict__ off,
                        int* __restrict__ aux, float* __restrict__ dinv,
                        int* __restrict__ degT, int* __restrict__ offR) {
    __shared__ int ls[256];
    int i = blockIdx.x * 256 + threadIdx.x;
    int c0 = 0, c1 = 0, c2 = 0, c3 = 0;
    if (i < NN) {
        c0 = deg_r[i]; c1 = deg_r[NN + i];
        c2 = deg_r[2 * NN + i]; c3 = deg_r[3 * NN + i];
    }
    int v = c0 + c1 + c2 + c3;
    ls[threadIdx.x] = v;
    __syncthreads();
    for (int s = 1; s < 256; s <<= 1) {
        int t = (threadIdx.x >= s) ? ls[threadIdx.x - s] : 0;
        __syncthreads();
        ls[threadIdx.x] += t;
        __syncthreads();
    }
    if (i < NN) {
        off[i] = ls[threadIdx.x] - v;       // block-local exclusive
        dinv[i] = rsqrtf((float)v + 1.0f);  // +1 self loop
        degT[i] = v;
        offR[i] = 0;
        offR[NN + i] = c0;
        offR[2 * NN + i] = c0 + c1;
        offR[3 * NN + i] = c0 + c1 + c2;
    }
    if (threadIdx.x == 255) aux[blockIdx.x] = ls[255];
}

__global__ void k_scan2(int* __restrict__ aux) {
    __shared__ int ls[256];
    int v = (threadIdx.x < NB1) ? aux[threadIdx.x] : 0;
    ls[threadIdx.x] = v;
    __syncthreads();
    for (int s = 1; s < 256; s <<= 1) {
        int t = (threadIdx.x >= s) ? ls[threadIdx.x - s] : 0;
        __syncthreads();
        ls[threadIdx.x] += t;
        __syncthreads();
    }
    if (threadIdx.x < NB1) aux[threadIdx.x] = ls[threadIdx.x] - v;
}

// ---------- CSR fill (no atomics), 4 edges/thread (quad shares one r-group) ----------
__global__ void k_fill(const int* __restrict__ src, const int* __restrict__ dst,
                       const int* __restrict__ off, const int* __restrict__ aux,
                       const int* __restrict__ offR, const int* __restrict__ rank,
                       int* __restrict__ csr) {
    int base = (blockIdx.x * 256 + threadIdx.x) * 4;
    if (base >= NE) return;
    int4 d4 = *(const int4*)&dst[base];
    int4 r4 = *(const int4*)&rank[base];
    int4 s4 = *(const int4*)&src[base];
    const int* oR = offR + ((base >> 9) & 3) * NN;   // 512 % 4 == 0 -> quad shares group
    csr[off[d4.x] + aux[d4.x >> 8] + oR[d4.x] + r4.x] = s4.x;
    csr[off[d4.y] + aux[d4.y >> 8] + oR[d4.y] + r4.y] = s4.y;
    csr[off[d4.z] + aux[d4.z >> 8] + oR[d4.z] + r4.z] = s4.z;
    csr[off[d4.w] + aux[d4.w >> 8] + oR[d4.w] + r4.w] = s4.w;
}

// ---------- pack W + Wout -> MFMA B-fragment order, bf16 ----------
__global__ void k_pack(const float* __restrict__ Ws, const float* __restrict__ Wout,
                       unsigned short* __restrict__ Wpk, unsigned short* __restrict__ Wopk) {
    int t = blockIdx.x * 256 + threadIdx.x;
    if (t < NL * 16384) {
        int l = t >> 14, r = t & 16383;
        int ks = r >> 12, ct = (r >> 9) & 7, lane = (r >> 3) & 63, i = r & 7;
        int k = ks * 32 + (lane >> 4) * 8 + i;
        int n = ct * 16 + (lane & 15);
        Wpk[t] = f2bf(Ws[l * 16384 + k * 128 + n]);
    } else if (t < NL * 16384 + 8192) {
        int r = t - NL * 16384;
        int ks = r >> 11, ct = (r >> 9) & 3, lane = (r >> 3) & 63, i = r & 7;
        int k = ks * 32 + (lane >> 4) * 8 + i;
        int n = ct * 16 + (lane & 15);
        Wopk[r] = f2bf(Wout[k * 64 + n]);
    }
}

// ---------- layer-0 GEMM: Hd(bf16) = (x_f32 @ W0) * dinv ----------
__global__ __launch_bounds__(256) void k_fg0(const float* __restrict__ X,
                                             const unsigned short* __restrict__ Wpk,
                                             const float* __restrict__ dinv,
                                             unsigned short* __restrict__ Hd) {
    int w = threadIdx.x >> 6, l = threadIdx.x & 63;
    int row0 = blockIdx.x * 64 + w * 16;
    int lo = l & 15, hi = l >> 4;
    int arow = row0 + lo;
    int crow = (arow < NN) ? arow : NN - 1;
    short8 frag[4];
#pragma unroll
    for (int g = 0; g < 4; g++) {
        int cs = g * 32 + hi * 8;
        float4 p0 = *(const float4*)&X[(size_t)crow * NH + cs];
        float4 p1 = *(const float4*)&X[(size_t)crow * NH + cs + 4];
        short8 f;
        f[0] = (short)f2bf(p0.x); f[1] = (short)f2bf(p0.y);
        f[2] = (short)f2bf(p0.z); f[3] = (short)f2bf(p0.w);
        f[4] = (short)f2bf(p1.x); f[5] = (short)f2bf(p1.y);
        f[6] = (short)f2bf(p1.z); f[7] = (short)f2bf(p1.w);
        frag[g] = f;
    }
    const short8* Wv = (const short8*)Wpk;
    int srow = row0 + hi * 4;
    float dv[4];
#pragma unroll
    for (int r = 0; r < 4; r++) dv[r] = (srow + r < NN) ? dinv[srow + r] : 0.0f;
#pragma unroll
    for (int ct = 0; ct < 8; ct++) {
        f32x4 acc = {0.0f, 0.0f, 0.0f, 0.0f};
#pragma unroll
        for (int g = 0; g < 4; g++)
            acc = __builtin_amdgcn_mfma_f32_16x16x32_bf16(frag[g], Wv[(g * 8 + ct) * 64 + l], acc, 0, 0, 0);
        int col = ct * 16 + lo;
#pragma unroll
        for (int r = 0; r < 4; r++) {
            int grow = srow + r;
            if (grow < NN) Hd[grow * NH + col] = f2bf(acc[r] * dv[r]);
        }
    }
}

// ---------- fused: x_l = BN+ReLU+res(AGG,prev); Hd = (x_l @ W) * dinv ----------
__global__ __launch_bounds__(256) void k_fg(const unsigned short* __restrict__ AGGb,
                                            const float* __restrict__ scale,
                                            const float* __restrict__ shift,
                                            const float* __restrict__ Xprev,
                                            float* __restrict__ Xout,
                                            const unsigned short* __restrict__ Wpk,
                                            const float* __restrict__ dinv,
                                            unsigned short* __restrict__ Hd) {
    int w = threadIdx.x >> 6, l = threadIdx.x & 63;
    int row0 = blockIdx.x * 64 + w * 16;
    int lo = l & 15, hi = l >> 4;
    int arow = row0 + lo;
    bool valid = arow < NN;
    int crow = valid ? arow : NN - 1;
    short8 frag[4];
#pragma unroll
    for (int g = 0; g < 4; g++) {
        int cs = g * 32 + hi * 8;
        uint4 ab = *(const uint4*)&AGGb[(size_t)crow * NH + cs];
        float4 p0 = *(const float4*)&Xprev[(size_t)crow * NH + cs];
        float4 p1 = *(const float4*)&Xprev[(size_t)crow * NH + cs + 4];
        float4 sc0 = *(const float4*)&scale[cs];
        float4 sc1 = *(const float4*)&scale[cs + 4];
        float4 sh0 = *(const float4*)&shift[cs];
        float4 sh1 = *(const float4*)&shift[cs + 4];
        float o0 = fmaxf(fmaf(bflo(ab.x), sc0.x, sh0.x), 0.0f) + p0.x;
        float o1 = fmaxf(fmaf(bfhi(ab.x), sc0.y, sh0.y), 0.0f) + p0.y;
        float o2 = fmaxf(fmaf(bflo(ab.y), sc0.z, sh0.z), 0.0f) + p0.z;
        float o3 = fmaxf(fmaf(bfhi(ab.y), sc0.w, sh0.w), 0.0f) + p0.w;
        float o4 = fmaxf(fmaf(bflo(ab.z), sc1.x, sh1.x), 0.0f) + p1.x;
        float o5 = fmaxf(fmaf(bfhi(ab.z), sc1.y, sh1.y), 0.0f) + p1.y;
        float o6 = fmaxf(fmaf(bflo(ab.w), sc1.z, sh1.z), 0.0f) + p1.z;
        float o7 = fmaxf(fmaf(bfhi(ab.w), sc1.w, sh1.w), 0.0f) + p1.w;
        if (valid) {
            float4 s0 = {o0, o1, o2, o3}, s1 = {o4, o5, o6, o7};
            *(float4*)&Xout[(size_t)arow * NH + cs] = s0;
            *(float4*)&Xout[(size_t)arow * NH + cs + 4] = s1;
        }
        short8 f;
        f[0] = (short)f2bf(o0); f[1] = (short)f2bf(o1);
        f[2] = (short)f2bf(o2); f[3] = (short)f2bf(o3);
        f[4] = (short)f2bf(o4); f[5] = (short)f2bf(o5);
        f[6] = (short)f2bf(o6); f[7] = (short)f2bf(o7);
        frag[g] = f;
    }
    const short8* Wv = (const short8*)Wpk;
    int srow = row0 + hi * 4;
    float dv[4];
#pragma unroll
    for (int r = 0; r < 4; r++) dv[r] = (srow + r < NN) ? dinv[srow + r] : 0.0f;
#pragma unroll
    for (int ct = 0; ct < 8; ct++) {
        f32x4 acc = {0.0f, 0.0f, 0.0f, 0.0f};
#pragma unroll
        for (int g = 0; g < 4; g++)
            acc = __builtin_amdgcn_mfma_f32_16x16x32_bf16(frag[g], Wv[(g * 8 + ct) * 64 + l], acc, 0, 0, 0);
        int col = ct * 16 + lo;
#pragma unroll
        for (int r = 0; r < 4; r++) {
            int grow = srow + r;
            if (grow < NN) Hd[grow * NH + col] = f2bf(acc[r] * dv[r]);
        }
    }
}

// ---------- fused final: x_4 = BN+ReLU+res; out = x_4 @ Wout + bout ----------
__global__ __launch_bounds__(256) void k_fgout(const unsigned short* __restrict__ AGGb,
                                               const float* __restrict__ scale,
                                               const float* __restrict__ shift,
                                               const float* __restrict__ Xprev,
                                               const unsigned short* __restrict__ Wpk,
                                               const float* __restrict__ b,
                                               float* __restrict__ out) {
    int w = threadIdx.x >> 6, l = threadIdx.x & 63;
    int row0 = blockIdx.x * 64 + w * 16;
    int lo = l & 15, hi = l >> 4;
    int arow = row0 + lo;
    int crow = (arow < NN) ? arow : NN - 1;
    short8 frag[4];
#pragma unroll
    for (int g = 0; g < 4; g++) {
        int cs = g * 32 + hi * 8;
        uint4 ab = *(const uint4*)&AGGb[(size_t)crow * NH + cs];
        float4 p0 = *(const float4*)&Xprev[(size_t)crow * NH + cs];
        float4 p1 = *(const float4*)&Xprev[(size_t)crow * NH + cs + 4];
        float4 sc0 = *(const float4*)&scale[cs];
        float4 sc1 = *(const float4*)&scale[cs + 4];
        float4 sh0 = *(const float4*)&shift[cs];
        float4 sh1 = *(const float4*)&shift[cs + 4];
        short8 f;
        f[0] = (short)f2bf(fmaxf(fmaf(bflo(ab.x), sc0.x, sh0.x), 0.0f) + p0.x);
        f[1] = (short)f2bf(fmaxf(fmaf(bfhi(ab.x), sc0.y, sh0.y), 0.0f) + p0.y);
        f[2] = (short)f2bf(fmaxf(fmaf(bflo(ab.y), sc0.z, sh0.z), 0.0f) + p0.z);
        f[3] = (short)f2bf(fmaxf(fmaf(bfhi(ab.y), sc0.w, sh0.w), 0.0f) + p0.w);
        f[4] = (short)f2bf(fmaxf(fmaf(bflo(ab.z), sc1.x, sh1.x), 0.0f) + p1.x);
        f[5] = (short)f2bf(fmaxf(fmaf(bfhi(ab.z), sc1.y, sh1.y), 0.0f) + p1.y);
        f[6] = (short)f2bf(fmaxf(fmaf(bflo(ab.w), sc1.z, sh1.z), 0.0f) + p1.z);
        f[7] = (short)f2bf(fmaxf(fmaf(bfhi(ab.w), sc1.w, sh1.w), 0.0f) + p1.w);
        frag[g] = f;
    }
    const short8* Wv = (const short8*)Wpk;
    int srow = row0 + hi * 4;
#pragma unroll
    for (int ct = 0; ct < 4; ct++) {
        f32x4 acc = {0.0f, 0.0f, 0.0f, 0.0f};
#pragma unroll
        for (int g = 0; g < 4; g++)
            acc = __builtin_amdgcn_mfma_f32_16x16x32_bf16(frag[g], Wv[(g * 4 + ct) * 64 + l], acc, 0, 0, 0);
        int col = ct * 16 + lo;
        float bb = b[col];
#pragma unroll
        for (int r = 0; r < 4; r++) {
            int grow = srow + r;
            if (grow < NN) out[grow * NO + col] = acc[r] + bb;
        }
    }
}

// ---------- CSR gather + fused BN partial stats (R6-proven structure) ----------
// 16 nodes/block, 16 threads/node, 4-deep unrolled edge loop.
__global__ __launch_bounds__(256) void k_gather(const unsigned short* __restrict__ Hd,
                                                const int* __restrict__ csr,
                                                const int* __restrict__ off,
                                                const int* __restrict__ aux,
                                                const int* __restrict__ degT,
                                                const float* __restrict__ dinv,
                                                unsigned short* __restrict__ AGGb,
                                                float* __restrict__ partial) {
    int b = blockIdx.x;
    int slot = threadIdx.x >> 4, q = threadIdx.x & 15;
    int g = b * 16 + slot;                 // NN % 16 == 0, always valid
    const uint4* Hv = (const uint4*)Hd;
    int o = off[g] + aux[g >> 8];
    int d = degT[g];
    uint4 h = Hv[g * 16 + q];              // self term
    float a0 = bflo(h.x), a1 = bfhi(h.x);
    float a2 = bflo(h.y), a3 = bfhi(h.y);
    float a4 = bflo(h.z), a5 = bfhi(h.z);
    float a6 = bflo(h.w), a7 = bfhi(h.w);
    int j = 0;
    for (; j + 4 <= d; j += 4) {
        int s0 = csr[o + j], s1 = csr[o + j + 1];
        int s2 = csr[o + j + 2], s3 = csr[o + j + 3];
        uint4 h0 = Hv[s0 * 16 + q];
        uint4 h1 = Hv[s1 * 16 + q];
        uint4 h2 = Hv[s2 * 16 + q];
        uint4 h3 = Hv[s3 * 16 + q];
        a0 += (bflo(h0.x) + bflo(h1.x)) + (bflo(h2.x) + bflo(h3.x));
        a1 += (bfhi(h0.x) + bfhi(h1.x)) + (bfhi(h2.x) + bfhi(h3.x));
        a2 += (bflo(h0.y) + bflo(h1.y)) + (bflo(h2.y) + bflo(h3.y));
        a3 += (bfhi(h0.y) + bfhi(h1.y)) + (bfhi(h2.y) + bfhi(h3.y));
        a4 += (bflo(h0.z) + bflo(h1.z)) + (bflo(h2.z) + bflo(h3.z));
        a5 += (bfhi(h0.z) + bfhi(h1.z)) + (bfhi(h2.z) + bfhi(h3.z));
        a6 += (bflo(h0.w) + bflo(h1.w)) + (bflo(h2.w) + bflo(h3.w));
        a7 += (bfhi(h0.w) + bfhi(h1.w)) + (bfhi(h2.w) + bfhi(h3.w));
    }
    for (; j < d; j++) {
        int s0 = csr[o + j];
        uint4 h0 = Hv[s0 * 16 + q];
        a0 += bflo(h0.x); a1 += bfhi(h0.x);
        a2 += bflo(h0.y); a3 += bfhi(h0.y);
        a4 += bflo(h0.z); a5 += bfhi(h0.z);
        a6 += bflo(h0.w); a7 += bfhi(h0.w);
    }
    float dv = dinv[g];
    a0 *= dv; a1 *= dv; a2 *= dv; a3 *= dv;
    a4 *= dv; a5 *= dv; a6 *= dv; a7 *= dv;
    uint4 u;
    u.x = pk(a0, a1); u.y = pk(a2, a3);
    u.z = pk(a4, a5); u.w = pk(a6, a7);
    ((uint4*)AGGb)[g * 16 + q] = u;
    // ---- fused BN partial stats: reduce across 16 node slots ----
    float t0 = a0 * a0, t1 = a1 * a1, t2 = a2 * a2, t3 = a3 * a3;
    float t4 = a4 * a4, t5 = a5 * a5, t6 = a6 * a6, t7 = a7 * a7;
#define RED(v) v += __shfl_xor(v, 16); v += __shfl_xor(v, 32);
    RED(a0) RED(a1) RED(a2) RED(a3) RED(a4) RED(a5) RED(a6) RED(a7)
    RED(t0) RED(t1) RED(t2) RED(t3) RED(t4) RED(t5) RED(t6) RED(t7)
#undef RED
    __shared__ float ws[4][16][16];
    int wv = threadIdx.x >> 6, lane = threadIdx.x & 63;
    if (lane < 16) {
        ws[wv][lane][0] = a0; ws[wv][lane][1] = a1;
        ws[wv][lane][2] = a2; ws[wv][lane][3] = a3;
        ws[wv][lane][4] = a4; ws[wv][lane][5] = a5;
        ws[wv][lane][6] = a6; ws[wv][lane][7] = a7;
        ws[wv][lane][8] = t0; ws[wv][lane][9] = t1;
        ws[wv][lane][10] = t2; ws[wv][lane][11] = t3;
        ws[wv][lane][12] = t4; ws[wv][lane][13] = t5;
        ws[wv][lane][14] = t6; ws[wv][lane][15] = t7;
    }
    __syncthreads();
    if (threadIdx.x < 16) {
        int qq = threadIdx.x;
#pragma unroll
        for (int k = 0; k < 8; k++) {
            float sv = ws[0][qq][k] + ws[1][qq][k] + ws[2][qq][k] + ws[3][qq][k];
            float qv = ws[0][qq][k + 8] + ws[1][qq][k + 8] + ws[2][qq][k + 8] + ws[3][qq][k + 8];
            partial[(size_t)b * 256 + qq * 8 + k] = sv;
            partial[(size_t)b * 256 + 128 + qq * 8 + k] = qv;
        }
    }
}

// ---------- reduce partials -> scale/shift ----------
__global__ __launch_bounds__(256) void k_statred(const float* __restrict__ partial,
                                                 const float* __restrict__ gamma,
                                                 const float* __restrict__ beta,
                                                 float* __restrict__ scale,
                                                 float* __restrict__ shift) {
    int s = blockIdx.x;   // column 0..127
    int t = threadIdx.x;
    float sum = 0.0f, sq = 0.0f;
    for (int k = t; k < NGB; k += 256) {
        sum += partial[(size_t)k * 256 + s];
        sq  += partial[(size_t)k * 256 + 128 + s];
    }
    __shared__ float ls[256], lq[256];
    ls[t] = sum; lq[t] = sq;
    __syncthreads();
    for (int st = 128; st > 0; st >>= 1) {
        if (t < st) { ls[t] += ls[t + st]; lq[t] += lq[t + st]; }
        __syncthreads();
    }
    if (t == 0) {
        float mean = ls[0] * (1.0f / NN);
        float var = lq[0] * (1.0f / NN) - mean * mean;
        float istd = rsqrtf(var + BN_EPS);
        float sc = istd * gamma[s];
        scale[s] = sc;
        shift[s] = beta[s] - mean * sc;
    }
}

extern "C" void kernel_launch(void* const* d_in, const int* in_sizes, int n_in,
                              void* d_out, int out_size, void* d_ws, size_t ws_size,
                              hipStream_t stream) {
    const float* x    = (const float*)d_in[0];
    const int*   ei   = (const int*)d_in[1];
    const float* Ws   = (const float*)d_in[2];
    const float* gam  = (const float*)d_in[4];
    const float* bet  = (const float*)d_in[5];
    const float* Wout = (const float*)d_in[6];
    const float* bout = (const float*)d_in[7];
    float* out = (float*)d_out;

    const int* src = ei;
    const int* dst = ei + NE;

    char* p = (char*)d_ws;
    auto alloc = [&](size_t bytes) { char* r = p; p += (bytes + 255) & ~(size_t)255; return r; };
    int*   deg_r = (int*)alloc((size_t)4 * NN * 4);
    int*   offR  = (int*)alloc((size_t)4 * NN * 4);
    int*   degT  = (int*)alloc(NN * 4);
    int*   off   = (int*)alloc(NN * 4);
    int*   rank  = (int*)alloc((size_t)NE * 4);
    int*   aux   = (int*)alloc(256 * 4);
    int*   csr   = (int*)alloc((size_t)NE * 4);
    float* dinv  = (float*)alloc(NN * 4);
    float* XA    = (float*)alloc((size_t)NN * NH * 4);
    float* XB    = (float*)alloc((size_t)NN * NH * 4);
    unsigned short* Hd   = (unsigned short*)alloc((size_t)NN * NH * 2);
    unsigned short* AGGb = (unsigned short*)alloc((size_t)NN * NH * 2);
    unsigned short* Wpk  = (unsigned short*)alloc((size_t)NL * NH * NH * 2);
    unsigned short* Wopk = (unsigned short*)alloc((size_t)NH * NO * 2);
    float* partial = (float*)alloc((size_t)NGB * 256 * 4);   // 3.2MB
    float* scale = (float*)alloc(NH * 4);
    float* shift = (float*)alloc(NH * 4);

    // ---- preprocessing ----
    hipMemsetAsync(deg_r, 0, (size_t)4 * NN * 4, stream);
    k_degrank<<<(NE / 2 + 255) / 256, 256, 0, stream>>>(dst, deg_r, rank);
    k_scan1<<<NB1, 256, 0, stream>>>(deg_r, off, aux, dinv, degT, offR);
    k_scan2<<<1, 256, 0, stream>>>(aux);
    k_fill<<<(NE / 4 + 255) / 256, 256, 0, stream>>>(src, dst, off, aux, offR, rank, csr);
    k_pack<<<(NL * 16384 + 8192 + 255) / 256, 256, 0, stream>>>(Ws, Wout, Wpk, Wopk);

    const int GB = (NN + 63) / 64;

    // ---- layer 0 GEMM from f32 input ----
    k_fg0<<<GB, 256, 0, stream>>>(x, Wpk, dinv, Hd);

    const float* xprev = x;
    for (int l = 0; l < NL; l++) {
        k_gather<<<NGB, 256, 0, stream>>>(Hd, csr, off, aux, degT, dinv, AGGb, partial);
        k_statred<<<128, 256, 0, stream>>>(partial, gam + l * NH, bet + l * NH, scale, shift);
        if (l < NL - 1) {
            float* Xout = (l & 1) ? XB : XA;
            k_fg<<<GB, 256, 0, stream>>>(AGGb, scale, shift, xprev, Xout,
                                         Wpk + (size_t)(l + 1) * 16384, dinv, Hd);
            xprev = Xout;
        } else {
            k_fgout<<<GB, 256, 0, stream>>>(AGGb, scale, shift, xprev, Wopk, bout, out);
        }
    }
}